// Round 1
// baseline (506.146 us; speedup 1.0000x reference)
//
#include <hip/hip_runtime.h>
#include <hip/hip_bf16.h>

// ComparatorNBit: A,B are [N,32] float32 in {0,1}, MSB first.
// a_eq_b = all bits equal; a_gt_b = (A > B) as 32-bit unsigned compare.
// Exact boolean semantics => pack bits into uint32 and integer-compare.
// Memory-bound: 512 MB in + 16 MB out => ~84 us floor at 6.3 TB/s.

__global__ void __launch_bounds__(256)
comparator_kernel(const float* __restrict__ A, const float* __restrict__ B,
                  float* __restrict__ out_gt, float* __restrict__ out_eq, int n) {
    int row = blockIdx.x * blockDim.x + threadIdx.x;
    if (row >= n) return;

    const float4* a4 = reinterpret_cast<const float4*>(A) + (size_t)row * 8;
    const float4* b4 = reinterpret_cast<const float4*>(B) + (size_t)row * 8;

    unsigned int abits = 0, bbits = 0;
#pragma unroll
    for (int j = 0; j < 8; ++j) {
        float4 a = a4[j];
        float4 b = b4[j];
        abits = (abits << 4) |
                ((unsigned)(a.x > 0.5f) << 3) | ((unsigned)(a.y > 0.5f) << 2) |
                ((unsigned)(a.z > 0.5f) << 1) | ((unsigned)(a.w > 0.5f));
        bbits = (bbits << 4) |
                ((unsigned)(b.x > 0.5f) << 3) | ((unsigned)(b.y > 0.5f) << 2) |
                ((unsigned)(b.z > 0.5f) << 1) | ((unsigned)(b.w > 0.5f));
    }

    out_gt[row] = (abits > bbits) ? 1.0f : 0.0f;
    out_eq[row] = (abits == bbits) ? 1.0f : 0.0f;
}

extern "C" void kernel_launch(void* const* d_in, const int* in_sizes, int n_in,
                              void* d_out, int out_size, void* d_ws, size_t ws_size,
                              hipStream_t stream) {
    const float* A = (const float*)d_in[0];
    const float* B = (const float*)d_in[1];
    float* out = (float*)d_out;

    const int BITS = 32;
    int n = in_sizes[0] / BITS;          // 2,000,000 rows

    float* out_gt = out;                  // first output: a_gt_b [N]
    float* out_eq = out + n;              // second output: a_eq_b [N]

    int block = 256;
    int grid = (n + block - 1) / block;
    comparator_kernel<<<grid, block, 0, stream>>>(A, B, out_gt, out_eq, n);
}

// Round 2
// 469.736 us; speedup vs baseline: 1.0775x; 1.0775x over previous
//
#include <hip/hip_runtime.h>
#include <hip/hip_bf16.h>

// ComparatorNBit: A,B are [N,32] float32 in {0,1}, MSB first.
// a_eq_b = all bits equal; a_gt_b = unsigned 32-bit compare of packed bits.
//
// R2: fully-coalesced layout. Each lane loads ONE float4 (16 B/lane,
// contiguous 1 KiB per wave-instruction). A wave covers 8 rows; lane L holds
// nibble (L&7) of row (L>>3). OR-reduce nibbles across 8-lane groups via
// 3 shfl_xor, then one lane per row compares + writes.
// R1 post-mortem: per-row layout (128 B lane stride) was transaction-bound
// (64 cachelines/instr), 169 us @ 1.7 TB/s with VALUBusy 6%.

__global__ void __launch_bounds__(256)
comparator_kernel(const float* __restrict__ A, const float* __restrict__ B,
                  float* __restrict__ out_gt, float* __restrict__ out_eq,
                  long long n) {
    long long tid = (long long)blockIdx.x * blockDim.x + threadIdx.x;
    long long totalVec = n * 8;            // number of float4s per input
    if (tid >= totalVec) return;

    const float4* a4 = reinterpret_cast<const float4*>(A);
    const float4* b4 = reinterpret_cast<const float4*>(B);
    float4 a = a4[tid];
    float4 b = b4[tid];

    // Pack 4 consecutive elements into a nibble, MSB-first (x is most significant).
    unsigned an = ((unsigned)(a.x > 0.5f) << 3) | ((unsigned)(a.y > 0.5f) << 2) |
                  ((unsigned)(a.z > 0.5f) << 1) |  (unsigned)(a.w > 0.5f);
    unsigned bn = ((unsigned)(b.x > 0.5f) << 3) | ((unsigned)(b.y > 0.5f) << 2) |
                  ((unsigned)(b.z > 0.5f) << 1) |  (unsigned)(b.w > 0.5f);

    int nib = (int)(tid & 7);              // 0 = most significant nibble of the row
    unsigned av = an << (4 * (7 - nib));
    unsigned bv = bn << (4 * (7 - nib));

    // OR-reduce across the 8-lane group (lanes sharing tid>>3).
    av |= __shfl_xor((int)av, 1, 64); bv |= __shfl_xor((int)bv, 1, 64);
    av |= __shfl_xor((int)av, 2, 64); bv |= __shfl_xor((int)bv, 2, 64);
    av |= __shfl_xor((int)av, 4, 64); bv |= __shfl_xor((int)bv, 4, 64);

    if (nib == 0) {
        long long row = tid >> 3;
        out_gt[row] = (av > bv)  ? 1.0f : 0.0f;
        out_eq[row] = (av == bv) ? 1.0f : 0.0f;
    }
}

extern "C" void kernel_launch(void* const* d_in, const int* in_sizes, int n_in,
                              void* d_out, int out_size, void* d_ws, size_t ws_size,
                              hipStream_t stream) {
    const float* A = (const float*)d_in[0];
    const float* B = (const float*)d_in[1];
    float* out = (float*)d_out;

    const int BITS = 32;
    long long n = in_sizes[0] / BITS;      // 2,000,000 rows

    float* out_gt = out;                   // output 0: a_gt_b [N]
    float* out_eq = out + n;               // output 1: a_eq_b [N]

    long long totalVec = n * 8;            // one thread per float4
    int block = 256;
    long long grid = (totalVec + block - 1) / block;
    comparator_kernel<<<(int)grid, block, 0, stream>>>(A, B, out_gt, out_eq, n);
}